// Round 1
// baseline (101.516 us; speedup 1.0000x reference)
//
#include <hip/hip_runtime.h>
#include <hip/hip_bf16.h>

// Problem constants (from reference):
//   v_latent [4,4,10,8,8] f32 -> split -> 32 video "images" [4,10,8]
//   p_tensor [32,4,10,8] f32  -> 32 patch images
//   encode: Conv2d(4->64, 3x3, pad=1) + ReLU + global-avg-pool -> [N,64]
//   scores = p_emb @ v_emb.T  [32,32]
//   pref = stable argsort(-scores) per row
//   greedy assign over 32 rounds, pid-ordered within round -> out int32[32]

#define HIDDEN 64
#define NPOS 32

// ---------------- Kernel 1: encode all 64 images (32 video + 32 patch) ----
// grid = 64 blocks (block n: n<32 video pos n, n>=32 patch n-32)
// block = 256 threads: lane oc = tid&63, segment seg = tid>>6 handles 20
// spatial positions. All lanes of a wave share seg -> LDS reads of the
// input tile are wave-uniform broadcasts (conflict-free).
__global__ __launch_bounds__(256) void encode_kernel(
    const float* __restrict__ v_latent,   // [4,4,10,8,8]
    const float* __restrict__ p_tensor,   // [32,4,10,8]
    const float* __restrict__ v_w,        // [64,4,3,3]
    const float* __restrict__ v_b,        // [64]
    const float* __restrict__ p_w,        // [64,4,3,3]
    const float* __restrict__ p_b,        // [64]
    float* __restrict__ emb)              // [64][64] out (rows 0..31 video)
{
    __shared__ float xpad[4][12][10];     // zero-padded input tile [ic][h+1][w+1]
    __shared__ float partial[4][64];

    const int n   = blockIdx.x;
    const int tid = threadIdx.x;
    const bool is_video = (n < 32);

    const float* w    = is_video ? v_w : p_w;
    const float* bias = is_video ? v_b : p_b;

    // Fill padded tile: 4*12*10 = 480 slots; interior <- input, border <- 0.
    // video mapping: x[ic][h][w] = v_latent[ic, n>>3, h, n&7, w]
    //   flat = ic*2560 + b*640 + h*64 + d*8 + w
    for (int s = tid; s < 480; s += 256) {
        const int ic  = s / 120;
        const int rem = s % 120;
        const int r   = rem / 10;   // padded row 0..11
        const int col = rem % 10;   // padded col 0..9
        float val = 0.f;
        if (r >= 1 && r <= 10 && col >= 1 && col <= 8) {
            const int h = r - 1, ww = col - 1;
            if (is_video) {
                const int b = n >> 3, d = n & 7;
                val = v_latent[ic * 2560 + b * 640 + h * 64 + d * 8 + ww];
            } else {
                val = p_tensor[(n - 32) * 320 + ic * 80 + h * 8 + ww];
            }
        }
        xpad[ic][r][col] = val;
    }

    const int oc  = tid & 63;
    const int seg = tid >> 6;

    // Per-lane conv weights for this output channel (36 regs).
    float wr[36];
#pragma unroll
    for (int i = 0; i < 36; i++) wr[i] = w[oc * 36 + i];
    const float bval = bias[oc];

    __syncthreads();

    // 20 spatial outputs per thread; sum ReLU'd conv results.
    float sum = 0.f;
#pragma unroll
    for (int pp = 0; pp < 20; pp++) {
        const int p = seg * 20 + pp;
        const int h = p >> 3;          // 0..9
        const int wcol = p & 7;        // 0..7
        float acc = bval;
#pragma unroll
        for (int ic = 0; ic < 4; ic++)
#pragma unroll
            for (int kh = 0; kh < 3; kh++)
#pragma unroll
                for (int kw = 0; kw < 3; kw++)
                    acc += xpad[ic][h + kh][wcol + kw] * wr[ic * 9 + kh * 3 + kw];
        sum += fmaxf(acc, 0.f);
    }
    partial[seg][oc] = sum;
    __syncthreads();

    if (seg == 0) {
        const float t = partial[0][oc] + partial[1][oc] + partial[2][oc] + partial[3][oc];
        emb[n * 64 + oc] = t * (1.f / 80.f);
    }
}

// ---------------- Kernel 2: scores + stable argsort + greedy assign -------
// Single wave (64 threads) => no inter-wave barrier hazards; __syncthreads
// degenerates to waitcnt.
__global__ __launch_bounds__(64) void match_kernel(
    const float* __restrict__ emb,  // [64][64]: rows 0..31 v_emb, 32..63 p_emb
    int* __restrict__ out)          // [32] int32
{
    __shared__ float ve[32][65];    // +1 pad: bank = (v+h) % 32, conflict-free
    __shared__ float pe[32][65];
    __shared__ float sc[32][33];
    __shared__ int   pref[32][32];
    __shared__ int   claim[32];
    __shared__ int   taken[32];

    const int tid = threadIdx.x;

    // Load 4096 floats of embeddings.
    for (int i = tid; i < 2048; i += 64) {
        const int r = i >> 6, c = i & 63;
        ve[r][c] = emb[i];          // v_emb rows
        pe[r][c] = emb[2048 + i];   // p_emb rows
    }
    __syncthreads();

    // scores[p][v] = dot(p_emb[p], v_emb[v]); 16 pairs per lane.
    for (int t = tid; t < 1024; t += 64) {
        const int p = t >> 5, v = t & 31;
        float acc = 0.f;
#pragma unroll
        for (int h = 0; h < 64; h++)
            acc += pe[p][h] * ve[v][h];
        sc[p][v] = acc;
    }
    __syncthreads();

    // Stable descending rank: r = #{u: s_u > s_v} + #{u<v: s_u == s_v}.
    // Then pref[p][r] = v  (inverse permutation == argsort result).
    for (int t = tid; t < 1024; t += 64) {
        const int p = t >> 5, v = t & 31;
        const float s = sc[p][v];
        int r = 0;
#pragma unroll
        for (int u = 0; u < 32; u++) {
            const float su = sc[p][u];
            r += (su > s) || (su == s && u < v);
        }
        pref[p][r] = v;
    }
    if (tid < 32) { claim[tid] = 64; taken[tid] = 0; }
    __syncthreads();

    // Greedy assignment, round-parallel. Within a round the lowest
    // unassigned pid proposing a free position wins == sequential semantics.
    int assign = -1;
    for (int r = 0; r < 32; r++) {
        int pos = 0;
        bool want = false;
        if (tid < 32 && assign < 0) {
            pos = pref[tid][r];
            if (!taken[pos]) {
                want = true;
                atomicMin(&claim[pos], tid);
            }
        }
        __syncthreads();
        if (want && claim[pos] == tid) {
            assign = pos;
            taken[pos] = 1;
            claim[pos] = 64;   // reset for next round
        }
        __syncthreads();
    }

    if (tid < 32) out[tid] = assign;
}

extern "C" void kernel_launch(void* const* d_in, const int* in_sizes, int n_in,
                              void* d_out, int out_size, void* d_ws, size_t ws_size,
                              hipStream_t stream) {
    const float* v_latent = (const float*)d_in[0];   // 2560
    const float* p_tensor = (const float*)d_in[1];   // 10240
    // d_in[2] = p_old_idx (unused by reference)
    const float* v_w = (const float*)d_in[3];        // 2304
    const float* v_b = (const float*)d_in[4];        // 64
    const float* p_w = (const float*)d_in[5];        // 2304
    const float* p_b = (const float*)d_in[6];        // 64

    int*   out = (int*)d_out;                        // 32 x int32
    float* emb = (float*)d_ws;                       // 64*64 f32 scratch

    encode_kernel<<<64, 256, 0, stream>>>(v_latent, p_tensor, v_w, v_b, p_w, p_b, emb);
    match_kernel<<<1, 64, 0, stream>>>(emb, out);
}

// Round 2
// 82.854 us; speedup vs baseline: 1.2252x; 1.2252x over previous
//
#include <hip/hip_runtime.h>
#include <hip/hip_bf16.h>

// Fully fused: encode (64 blocks, one image each) + last-arriving block runs
// scores -> stable argsort -> greedy assignment. Cross-block handoff via
// device-scope atomic arrival counter + __threadfence (release/acquire).
// No block waits on another -> deadlock-free under any dispatch order.

#define HIDDEN 64
#define NPOS 32

__global__ __launch_bounds__(256) void fused_kernel(
    const float* __restrict__ v_latent,   // [4,4,10,8,8]
    const float* __restrict__ p_tensor,   // [32,4,10,8]
    const float* __restrict__ v_w,        // [64,4,3,3]
    const float* __restrict__ v_b,        // [64]
    const float* __restrict__ p_w,        // [64,4,3,3]
    const float* __restrict__ p_b,        // [64]
    float* emb,                           // ws: [64][64] (rows 0..31 video)
    int*   counter,                       // ws: arrival counter (memset to 0)
    int* __restrict__ out)                // [32] int32
{
    // ---- encode-phase LDS ----
    __shared__ float xpad[4][12][10];     // zero-padded input tile
    __shared__ float partial[4][64];
    __shared__ int   last_flag;
    // ---- match-phase LDS (only last block touches) ----
    __shared__ float ve[32][65];          // +1 pad: bank (v+h)%32, conflict-free
    __shared__ float pe[32][65];
    __shared__ float sc[32][33];
    __shared__ int   pref[32][32];
    __shared__ int   claim[32];
    __shared__ int   taken[32];

    const int n   = blockIdx.x;
    const int tid = threadIdx.x;
    const bool is_video = (n < 32);

    const float* w    = is_video ? v_w : p_w;
    const float* bias = is_video ? v_b : p_b;

    // Fill padded tile: 4*12*10 = 480 slots; interior <- input, border <- 0.
    // video: x[ic][h][w] = v_latent[ic, n>>3, h, n&7, w]
    for (int s = tid; s < 480; s += 256) {
        const int ic  = s / 120;
        const int rem = s % 120;
        const int r   = rem / 10;
        const int col = rem % 10;
        float val = 0.f;
        if (r >= 1 && r <= 10 && col >= 1 && col <= 8) {
            const int h = r - 1, ww = col - 1;
            if (is_video) {
                const int b = n >> 3, d = n & 7;
                val = v_latent[ic * 2560 + b * 640 + h * 64 + d * 8 + ww];
            } else {
                val = p_tensor[(n - 32) * 320 + ic * 80 + h * 8 + ww];
            }
        }
        xpad[ic][r][col] = val;
    }

    const int oc  = tid & 63;
    const int seg = tid >> 6;

    // 36 conv weights for this oc, vectorized: 144 B aligned -> 9 float4.
    float wr[36];
    {
        const float4* w4 = (const float4*)(w + oc * 36);
#pragma unroll
        for (int i = 0; i < 9; i++) {
            const float4 q = w4[i];
            wr[i * 4 + 0] = q.x; wr[i * 4 + 1] = q.y;
            wr[i * 4 + 2] = q.z; wr[i * 4 + 3] = q.w;
        }
    }
    const float bval = bias[oc];

    __syncthreads();

    // 20 spatial outputs per thread; all lanes of a wave share (seg,pp) ->
    // xpad reads are wave-uniform broadcasts.
    float sum = 0.f;
#pragma unroll
    for (int pp = 0; pp < 20; pp++) {
        const int p = seg * 20 + pp;
        const int h = p >> 3, wcol = p & 7;
        float acc = bval;
#pragma unroll
        for (int ic = 0; ic < 4; ic++)
#pragma unroll
            for (int kh = 0; kh < 3; kh++)
#pragma unroll
                for (int kw = 0; kw < 3; kw++)
                    acc += xpad[ic][h + kh][wcol + kw] * wr[ic * 9 + kh * 3 + kw];
        sum += fmaxf(acc, 0.f);
    }
    partial[seg][oc] = sum;
    __syncthreads();

    if (seg == 0) {
        const float t = partial[0][oc] + partial[1][oc] + partial[2][oc] + partial[3][oc];
        emb[n * 64 + oc] = t * (1.f / 80.f);
    }
    __syncthreads();  // drains vmcnt: all emb writes of this block complete

    // ---- arrival: release our emb row, detect last block ----
    if (tid == 0) {
        __threadfence();                       // release
        const int old = atomicAdd(counter, 1); // device scope
        last_flag = (old == 63);
        if (last_flag) __threadfence();        // acquire
    }
    __syncthreads();
    if (!last_flag) return;

    // =================== match phase (last block, 256 threads) ============
    for (int i = tid; i < 2048; i += 256) {
        const int r = i >> 6, c = i & 63;
        ve[r][c] = emb[i];          // v_emb rows 0..31
        pe[r][c] = emb[2048 + i];   // p_emb rows 0..31
    }
    if (tid < 32) { claim[tid] = 64; taken[tid] = 0; }
    __syncthreads();

    // scores[p][v] = dot(p_emb[p], v_emb[v]); 4 pairs per thread.
    for (int t = tid; t < 1024; t += 256) {
        const int p = t >> 5, v = t & 31;
        float acc = 0.f;
#pragma unroll
        for (int h = 0; h < 64; h++)
            acc += pe[p][h] * ve[v][h];
        sc[p][v] = acc;
    }
    __syncthreads();

    // Stable descending rank: r = #{u: s_u > s_v} + #{u<v: s_u == s_v};
    // pref[p][r] = v  (== jnp.argsort(-scores) row, stable).
    for (int t = tid; t < 1024; t += 256) {
        const int p = t >> 5, v = t & 31;
        const float s = sc[p][v];
        int r = 0;
#pragma unroll
        for (int u = 0; u < 32; u++) {
            const float su = sc[p][u];
            r += (su > s) || (su == s && u < v);
        }
        pref[p][r] = v;
    }
    __syncthreads();

    // Greedy assignment, round-parallel: lowest unassigned pid proposing a
    // free position wins (atomicMin) == sequential reference semantics.
    int assign = -1;
    for (int r = 0; r < 32; r++) {
        int pos = 0;
        bool want = false;
        if (tid < 32 && assign < 0) {
            pos = pref[tid][r];
            if (!taken[pos]) {
                want = true;
                atomicMin(&claim[pos], tid);
            }
        }
        __syncthreads();
        if (want && claim[pos] == tid) {
            assign = pos;
            taken[pos] = 1;
            claim[pos] = 64;
        }
        __syncthreads();
    }

    if (tid < 32) out[tid] = assign;
}

extern "C" void kernel_launch(void* const* d_in, const int* in_sizes, int n_in,
                              void* d_out, int out_size, void* d_ws, size_t ws_size,
                              hipStream_t stream) {
    const float* v_latent = (const float*)d_in[0];
    const float* p_tensor = (const float*)d_in[1];
    // d_in[2] = p_old_idx (unused by reference)
    const float* v_w = (const float*)d_in[3];
    const float* v_b = (const float*)d_in[4];
    const float* p_w = (const float*)d_in[5];
    const float* p_b = (const float*)d_in[6];

    int*   out     = (int*)d_out;
    float* emb     = (float*)d_ws;                         // 16 KB
    int*   counter = (int*)((char*)d_ws + 64 * 64 * 4);    // 4 B after emb

    hipMemsetAsync(counter, 0, sizeof(int), stream);
    fused_kernel<<<64, 256, 0, stream>>>(v_latent, p_tensor, v_w, v_b, p_w, p_b,
                                         emb, counter, out);
}